// Round 6
// baseline (577.335 us; speedup 1.0000x reference)
//
#include <hip/hip_runtime.h>
#include <math.h>

// Problem constants (fixed by the reference)
#define B_ 4
#define T_ 2048
#define D_ 2048
#define L_ 2048
#define KW 4
#define M_ (B_*T_)       // 8192 rows for all GEMMs

typedef unsigned short u16;
typedef unsigned short u16x8 __attribute__((ext_vector_type(8)));
typedef __bf16 bf16x8 __attribute__((ext_vector_type(8)));
typedef float f32x4 __attribute__((ext_vector_type(4)));

__device__ __forceinline__ u16 f2bf(float f) {       // RNE f32 -> bf16 bits
    unsigned u = __float_as_uint(f);
    u += 0x7fffu + ((u >> 16) & 1u);
    return (u16)(u >> 16);
}
__device__ __forceinline__ float bf2f(u16 h) {
    return __uint_as_float(((unsigned)h) << 16);
}
__device__ __forceinline__ float gelu_exact(float v) {
    return 0.5f * v * (1.0f + erff(v * 0.70710678118654752440f));
}
__device__ __forceinline__ float sigmoidf_(float v) {
    return 1.0f / (1.0f + __expf(-v));
}
__device__ __forceinline__ void gload16(const void* g, void* l) {
    __builtin_amdgcn_global_load_lds(
        (const __attribute__((address_space(1))) void*)g,
        (__attribute__((address_space(3))) void*)l,
        16, 0, 0);
}
// Phase boundary: raw s_barrier + FULL scheduling fence. sched_barrier(0)
// prevents the compiler from sinking register-only MFMAs (and their
// operand lgkmcnt waits) past the barrier — the liveness ledger requires
// every MFMA to execute inside its phase (rule #18 analog).
__device__ __forceinline__ void barf() {
    __builtin_amdgcn_sched_barrier(0);
    __builtin_amdgcn_s_barrier();
    __builtin_amdgcn_sched_barrier(0);
}

// ---------------- cast x -> bf16 ----------------
__global__ __launch_bounds__(256)
void castx_kernel(const float* __restrict__ in, u16* __restrict__ out)
{
    const int i = blockIdx.x * 256 + threadIdx.x;      // one float4
    float4 v = ((const float4*)in)[i];
    ushort4 o;
    o.x = f2bf(v.x); o.y = f2bf(v.y); o.z = f2bf(v.z); o.w = f2bf(v.w);
    ((ushort4*)out)[i] = o;
}

// ---------------- transpose-cast weight [K,N] f32 -> [N,K] bf16 ----------------
__global__ __launch_bounds__(256)
void transcast_kernel(const float* __restrict__ in, u16* __restrict__ out,
                      int Kd, int Nd)
{
    __shared__ float tile[32][33];
    const int bx = blockIdx.x;          // along N
    const int by = blockIdx.y;          // along K
    const int tx = threadIdx.x & 31;
    const int ty = threadIdx.x >> 5;    // 0..7
    #pragma unroll
    for (int j = 0; j < 4; ++j) {
        const int r = by*32 + ty + j*8;
        tile[ty + j*8][tx] = in[(size_t)r * Nd + bx*32 + tx];
    }
    __syncthreads();
    #pragma unroll
    for (int j = 0; j < 4; ++j) {
        const int n = bx*32 + ty + j*8;
        out[(size_t)n * Kd + by*32 + tx] = f2bf(tile[tx][ty + j*8]);
    }
}

// =====================================================================
// bf16 MFMA GEMM: C[M,N] = epi(A[M,K] @ BT[N,K]^T + bias)
// 256x128 tile, BK=64, 8 waves (4M x 2N), per-wave 64x64, 512 threads.
// 4 phases/K-tile, ONE barrier per phase, fragment prefetch one phase
// ahead. MFMA(p) is gated by the compiler's precise operand lgkmcnt on
// fragments read in phase p-1; sched_barrier(0) at phase ends pins each
// MFMA inside its phase, so "wave passed its phase barrier" implies
// "its fragment ds_reads completed".
//
// Region liveness (stage-over is always >= 1 barrier after the region's
// last consumption, whose operand-wait completed the reads):
//   AH0(g): read-issue phi4(g-1), consumed phi1(g) -> staged phi2(g)  OK
//   BH1(g): read-issue phi1(g),  consumed phi2(g) -> staged phi3(g)  OK
//   AH1(g): read-issue phi2(g),  consumed phi3(g) -> staged phi4(g)  OK
//   BH0(g): read-issue phi4(g-1), consumed phi1(g) -> staged phi4(g)  OK
// vmcnt ledger (per wave, 6 loads/K-tile: AH0=2,BH1=1,AH1=2,BH0=1):
//   at phi3(g)-end, outstanding = tile(g+1)'s 6 + AH0(g+2)[2] +
//   BH1(g+2)[1] = 9; vmcnt(3) BEFORE the phi3 barrier retires tile g+1
//   -> after the barrier every wave may read ANY wave's tile-(g+1) data
//   (cross-wave visibility = issuer vmcnt + barrier; vmcnt is per-wave,
//   which is why the wait must precede the barrier — round-5 bug).
//   Tail: g=NT-2 -> vmcnt(0); g=NT-1 -> nothing outstanding.
// Prologue: stage tiles 0,1 (12 loads), vmcnt(6) retires tile 0,
// barrier, prefetch F1(0). NT even (32 here) for bf0A/bf0B alternation.
// =====================================================================
__device__ __forceinline__ void store_out(float* C, size_t idx, float v) { C[idx] = v; }
__device__ __forceinline__ void store_out(u16*   C, size_t idx, float v) { C[idx] = f2bf(v); }

template<int EPI, typename OutT>   // EPI: 0 = bias, 1 = gelu, 2 = sigmoid
__global__ __launch_bounds__(512)
void mgemm_kernel(const u16* __restrict__ A, const u16* __restrict__ BT,
                  const float* __restrict__ bias, OutT* __restrict__ C,
                  int M, int N, int K)
{
    __shared__ __align__(16) u16 lds[49152];   // A: 2x16384 (64KB) | B: 2x8192 (32KB)
    u16* ldsB = lds + 32768;

    const int tid  = threadIdx.x;
    const int wave = tid >> 6;          // 0..7
    const int lane = tid & 63;

    // bijective XCD swizzle (nwg = 512, %8 == 0)
    const int nbx = N >> 7;                       // N/128
    const int nwg = nbx * (M >> 8);
    const int bid = blockIdx.x;
    const int li  = (bid & 7) * (nwg >> 3) + (bid >> 3);
    const int bm  = (li / nbx) * 256;
    const int bn  = (li % nbx) * 128;

    const int wm = wave >> 1;           // 0..3 (M quarter of 64 rows)
    const int wn = wave & 1;            // 0..1 (N half of 64 cols)
    const int lr = lane & 15;
    const int q  = lane >> 4;
    const int sw = lane & 7;

    const int grow8 = lane >> 3;              // row within 8-row chunk
    const int gslot = (lane & 7) ^ grow8;     // pre-swizzled global k-slot

    const int NT = K >> 6;              // 32 K-tiles (even)

    // stage chunk assignment (chunk = 8 rows x 128B)
    const int cA0 = (wave >> 1) * 8 + (wave & 1) * 2;   // AH0: cA0,cA0+1; AH1: +4
    const int cB0 = (wave >> 2) * 8 + (wave & 3);       // BH0: cB0; BH1: +4

    const u16* gA0 = A  + (size_t)(bm + (cA0    )*8 + grow8) * K + gslot*8;
    const u16* gA1 = A  + (size_t)(bm + (cA0 + 1)*8 + grow8) * K + gslot*8;
    const u16* gA2 = A  + (size_t)(bm + (cA0 + 4)*8 + grow8) * K + gslot*8;
    const u16* gA3 = A  + (size_t)(bm + (cA0 + 5)*8 + grow8) * K + gslot*8;
    const u16* gB0 = BT + (size_t)(bn + (cB0    )*8 + grow8) * K + gslot*8;
    const u16* gB1 = BT + (size_t)(bn + (cB0 + 4)*8 + grow8) * K + gslot*8;
    const int dA0 = (cA0    )*512 + lane*8, dA1 = (cA0+1)*512 + lane*8;
    const int dA2 = (cA0 + 4)*512 + lane*8, dA3 = (cA0+5)*512 + lane*8;
    const int dB0 = (cB0    )*512 + lane*8, dB1 = (cB0+4)*512 + lane*8;

    auto ST_AH0 = [&](int g){ u16* b = lds  + (g&1)*16384; const size_t kg = (size_t)g<<6;
        gload16(gA0+kg, &b[dA0]); gload16(gA1+kg, &b[dA1]); };
    auto ST_AH1 = [&](int g){ u16* b = lds  + (g&1)*16384; const size_t kg = (size_t)g<<6;
        gload16(gA2+kg, &b[dA2]); gload16(gA3+kg, &b[dA3]); };
    auto ST_BH0 = [&](int g){ u16* b = ldsB + (g&1)*8192;  const size_t kg = (size_t)g<<6;
        gload16(gB0+kg, &b[dB0]); };
    auto ST_BH1 = [&](int g){ u16* b = ldsB + (g&1)*8192;  const size_t kg = (size_t)g<<6;
        gload16(gB1+kg, &b[dB1]); };

    // swizzled read slots: global slot s of row r lives at LDS slot s^(r&7); r&7==sw
    const int ks0 = ((    q) ^ sw) * 8;
    const int ks1 = ((4 + q) ^ sw) * 8;

    auto LD_AF = [&](const u16* Ab, int half, bf16x8 (&dst)[2][2]) {
        #pragma unroll
        for (int i = 0; i < 2; ++i) {
            const int ro = (wm*64 + half*32 + i*16 + lr) * 64;
            dst[i][0] = *(const bf16x8*)&Ab[ro + ks0];
            dst[i][1] = *(const bf16x8*)&Ab[ro + ks1];
        }
    };
    auto LD_BF = [&](const u16* Bb, int half, bf16x8 (&dst)[2][2]) {
        #pragma unroll
        for (int j = 0; j < 2; ++j) {
            const int ro = (wn*64 + half*32 + j*16 + lr) * 64;
            dst[j][0] = *(const bf16x8*)&Bb[ro + ks0];
            dst[j][1] = *(const bf16x8*)&Bb[ro + ks1];
        }
    };

    f32x4 acc[4][4] = {};
    bf16x8 af0[2][2], af1[2][2], bf0A[2][2], bf0B[2][2], bf1[2][2];

    auto MM = [&](int mh, int nh, bf16x8 (&a)[2][2], bf16x8 (&b)[2][2]) {
        __builtin_amdgcn_s_setprio(1);
        #pragma unroll
        for (int ks = 0; ks < 2; ++ks)
            #pragma unroll
            for (int i = 0; i < 2; ++i)
                #pragma unroll
                for (int j = 0; j < 2; ++j)
                    acc[mh*2+i][nh*2+j] = __builtin_amdgcn_mfma_f32_16x16x32_bf16(
                        a[i][ks], b[j][ks], acc[mh*2+i][nh*2+j], 0, 0, 0);
        __builtin_amdgcn_s_setprio(0);
    };

    // ---- prologue ----
    ST_AH0(0); ST_BH1(0); ST_AH1(0); ST_BH0(0);   // tile 0 (6 loads)
    ST_AH0(1); ST_BH1(1); ST_AH1(1); ST_BH0(1);   // tile 1 (6 loads)
    asm volatile("s_waitcnt vmcnt(6)" ::: "memory");   // retire tile 0 (before barrier!)
    barf();
    LD_AF(lds, 0, af0);        // prefetch F1(0) — tile 0 data visible to all waves
    LD_BF(ldsB, 0, bf0A);

    auto ktile = [&](int g, bf16x8 (&bfc)[2][2], bf16x8 (&bfn)[2][2]) {
        const u16* Ab = lds  + (g&1)*16384;
        const u16* Bb = ldsB + (g&1)*8192;
        const bool s1 = (g + 1 < NT), s2 = (g + 2 < NT);

        // phi1: LD bf1(g) | MM(0,0) on prefetched af0,bfc
        LD_BF(Bb, 1, bf1);
        MM(0, 0, af0, bfc);
        barf();

        // phi2: LD af1(g) | stage AH0(g+2) | MM(0,1)
        LD_AF(Ab, 1, af1);
        if (s2) ST_AH0(g + 2);
        MM(0, 1, af0, bf1);
        barf();

        // phi3: stage BH1(g+2) | MM(1,1) | retire tile g+1 BEFORE the barrier
        if (s2) ST_BH1(g + 2);
        MM(1, 1, af1, bf1);
        if (s1) {
            if (s2) { asm volatile("s_waitcnt vmcnt(3)" ::: "memory"); }
            else    { asm volatile("s_waitcnt vmcnt(0)" ::: "memory"); }
        }
        barf();

        // phi4: prefetch F1(g+1) (cross-wave safe now) | stage AH1/BH0(g+2) | MM(1,0)
        if (s1) {
            const u16* AbN = lds  + ((g+1)&1)*16384;
            const u16* BbN = ldsB + ((g+1)&1)*8192;
            LD_AF(AbN, 0, af0);
            LD_BF(BbN, 0, bfn);
            if (s2) { ST_AH1(g + 2); ST_BH0(g + 2); }
        }
        MM(1, 0, af1, bfc);
        barf();
    };

    for (int g = 0; g < NT; g += 2) {
        ktile(g,     bf0A, bf0B);
        ktile(g + 1, bf0B, bf0A);
    }

    // ---- epilogue; C/D layout: col = lane&15, row = (lane>>4)*4 + reg ----
    // nj innermost so each 128B line completes in 4 consecutive stores.
    const int orow = (lane >> 4) * 4;
    float bv[4];
    #pragma unroll
    for (int nj = 0; nj < 4; ++nj) bv[nj] = bias[bn + wn*64 + nj*16 + lr];
    #pragma unroll
    for (int mi = 0; mi < 4; ++mi) {
        #pragma unroll
        for (int r = 0; r < 4; ++r) {
            const int row = bm + wm*64 + mi*16 + orow + r;
            const size_t rb = (size_t)row * N + bn + wn*64 + lr;
            #pragma unroll
            for (int nj = 0; nj < 4; ++nj) {
                float v = acc[mi][nj][r] + bv[nj];
                if (EPI == 1)      v = gelu_exact(v);
                else if (EPI == 2) v = sigmoidf_(v);
                store_out(C, rb + nj*16, v);
            }
        }
    }
}

// ---------------- causal depthwise conv1d, width 4 (bf16 in/out) ----------------
__global__ __launch_bounds__(256)
void conv_kernel(const u16* __restrict__ xb, const float* __restrict__ cw,
                 const float* __restrict__ cb, u16* __restrict__ out)
{
    const int idx = blockIdx.x * 256 + threadIdx.x;    // one 8-elem chunk
    const int NL8 = L_ / 8;
    const int l = (idx % NL8) * 8;
    const int bt = idx / NL8;
    const int t = bt & (T_ - 1);
    float acc[8];
    #pragma unroll
    for (int j = 0; j < 8; ++j) acc[j] = cb[l + j];
    #pragma unroll
    for (int k = 0; k < KW; ++k) {
        const int ts = t - (KW-1) + k;
        if (ts >= 0) {
            u16x8 xv = *(const u16x8*)(xb + ((size_t)(bt - (KW-1-k))) * L_ + l);
            #pragma unroll
            for (int j = 0; j < 8; ++j)
                acc[j] = fmaf(cw[k*L_ + l + j], bf2f(xv[j]), acc[j]);
        }
    }
    u16x8 o;
    #pragma unroll
    for (int j = 0; j < 8; ++j) o[j] = f2bf(acc[j]);
    *(u16x8*)(out + (size_t)bt * L_ + l) = o;
}

// ---------------- RG-LRU pointwise (in-place: gx->a, ga->nx), bf16 ----------------
__global__ __launch_bounds__(256)
void rglru_kernel(const u16* __restrict__ conv, u16* __restrict__ gxa,
                  u16* __restrict__ ganx, const float* __restrict__ ap)
{
    const int idx = blockIdx.x * 256 + threadIdx.x;
    const int NL8 = L_ / 8;
    const int l = (idx % NL8) * 8;
    const int bt = idx / NL8;
    const int t = bt & (T_ - 1);
    const size_t off = (size_t)bt * L_ + l;
    u16x8 gx = *(u16x8*)(gxa + off);
    u16x8 ga = *(u16x8*)(ganx + off);
    u16x8 cv = *(const u16x8*)(conv + off);
    u16x8 av, nxv;
    #pragma unroll
    for (int j = 0; j < 8; ++j) {
        float p  = ap[l + j];
        float sp = log1pf(expf(p));             // softplus(a_param)
        float la = -8.0f * bf2f(ga[j]) * sp;    // log_a
        float a  = expf(la);
        float mult = sqrtf(fmaxf(0.f, 1.0f - a*a));
        if (t == 0) { a = 0.f; mult = 1.f; }
        av[j]  = f2bf(a);
        nxv[j] = f2bf(bf2f(gx[j]) * bf2f(cv[j]) * mult);
    }
    *(u16x8*)(gxa + off)  = av;
    *(u16x8*)(ganx + off) = nxv;
}

// ---------------- chunked linear scan: h_t = a_t*h_{t-1} + x_t ----------------
#define CHUNKS 32
#define CLEN (T_ / CHUNKS)   // 64

__global__ __launch_bounds__(256)
void scan1_kernel(const u16* __restrict__ Ab, const u16* __restrict__ Xb,
                  float* __restrict__ Pb, float* __restrict__ Sb)
{
    const int l = blockIdx.x * 256 + threadIdx.x;
    const int c = blockIdx.y;
    const int b = blockIdx.z;
    size_t base = ((size_t)b * T_ + (size_t)c * CLEN) * L_ + l;
    float h = 0.f, P = 1.f;
    #pragma unroll 4
    for (int t = 0; t < CLEN; ++t) {
        float a = bf2f(Ab[base + (size_t)t * L_]);
        float x = bf2f(Xb[base + (size_t)t * L_]);
        h = fmaf(a, h, x);
        P *= a;
    }
    const size_t o = ((size_t)b * CHUNKS + c) * L_ + l;
    Pb[o] = P;
    Sb[o] = h;
}

__global__ __launch_bounds__(256)
void scan2_kernel(const float* __restrict__ Pb, const float* __restrict__ Sb,
                  float* __restrict__ Hin, float* __restrict__ hn)
{
    const int idx = blockIdx.x * 256 + threadIdx.x;  // B*L threads
    const int l = idx & (L_ - 1);
    const int b = idx >> 11;
    float h = 0.f;
    for (int c = 0; c < CHUNKS; ++c) {
        const size_t o = ((size_t)b * CHUNKS + c) * L_ + l;
        Hin[o] = h;
        h = fmaf(Pb[o], h, Sb[o]);
    }
    hn[(size_t)b * L_ + l] = h;
}

__global__ __launch_bounds__(256)
void scan3_kernel(const u16* __restrict__ Ab, const u16* __restrict__ Xb,
                  const float* __restrict__ Hin, const u16* __restrict__ Yb,
                  u16* __restrict__ Zb)
{
    const int l = blockIdx.x * 256 + threadIdx.x;
    const int c = blockIdx.y;
    const int b = blockIdx.z;
    float h = Hin[((size_t)b * CHUNKS + c) * L_ + l];
    size_t base = ((size_t)b * T_ + (size_t)c * CLEN) * L_ + l;
    #pragma unroll 4
    for (int t = 0; t < CLEN; ++t) {
        const size_t o = base + (size_t)t * L_;
        h = fmaf(bf2f(Ab[o]), h, bf2f(Xb[o]));
        Zb[o] = f2bf(h * bf2f(Yb[o]));
    }
}

// ---------------- launch ----------------
extern "C" void kernel_launch(void* const* d_in, const int* in_sizes, int n_in,
                              void* d_out, int out_size, void* d_ws, size_t ws_size,
                              hipStream_t stream)
{
    const float* x     = (const float*)d_in[0];
    const float* w_y   = (const float*)d_in[1];
    const float* b_y   = (const float*)d_in[2];
    const float* w_x   = (const float*)d_in[3];
    const float* b_x   = (const float*)d_in[4];
    const float* cw    = (const float*)d_in[5];
    const float* cb    = (const float*)d_in[6];
    const float* ap    = (const float*)d_in[7];
    const float* w_ig  = (const float*)d_in[8];
    const float* b_ig  = (const float*)d_in[9];
    const float* w_ag  = (const float*)d_in[10];
    const float* b_ag  = (const float*)d_in[11];
    const float* w_out = (const float*)d_in[12];
    const float* b_out = (const float*)d_in[13];

    float* out = (float*)d_out;               // [B,T,D] flat
    float* hn  = out + (size_t)M_ * D_;       // [B,L] appended

    // workspace layout (liveness-aliased, peak 192 MB)
    const size_t MB = 1u << 20;
    char* w = (char*)d_ws;
    u16*  xbf   = (u16*)(w + 0);        // [M,D] bf16 — dead after GEMM2
    u16*  wigb  = (u16*)(w + 0);        // [L,L]T bf16 — after xbf dead
    u16*  wagb  = (u16*)(w + 8*MB);
    u16*  zb    = (u16*)(w + 0);        // [M,L] bf16 — after GEMM4
    u16*  ybf   = (u16*)(w + 32*MB);    // [M,L] bf16
    u16*  xbbf  = (u16*)(w + 64*MB);    // [M,L] bf16 — dead after conv
    u16*  woutb = (u16*)(w + 64*MB);    // after xbbf dead
    float* Pb   = (float*)(w + 72*MB);
    float* Sb   = (float*)(w + 73*MB);
    float* Hin  = (float*)(w + 74*MB);
    u16*  wyb   = (u16*)(w + 96*MB);    // weights dead after GEMM2
    u16*  wxb   = (u16*)(w + 104*MB);
    u16*  convb = (u16*)(w + 96*MB);    // [M,L] bf16 — after wyb/wxb dead
    u16*  gx    = (u16*)(w + 128*MB);   // -> a  (in-place)
    u16*  ga    = (u16*)(w + 160*MB);   // -> nx (in-place)

    const dim3 blk(256);
    const dim3 blkG(512);
    const dim3 gG((L_/128) * (M_/256));             // 512 blocks, 1-D
    const dim3 gT(2048/32, 2048/32);                // transpose grids
    const int  gE8 = (M_ * L_ / 8) / 256;           // 8-wide elementwise
    const dim3 gScan(L_/256, CHUNKS, B_);

    // casts for stage 1
    hipLaunchKernelGGL(castx_kernel, dim3((M_*D_/4)/256), blk, 0, stream, x, xbf);
    hipLaunchKernelGGL(transcast_kernel, gT, blk, 0, stream, w_y, wyb, D_, L_);
    hipLaunchKernelGGL(transcast_kernel, gT, blk, 0, stream, w_x, wxb, D_, L_);
    // 1. y = GELU(x@w_y + b_y) -> ybf
    hipLaunchKernelGGL((mgemm_kernel<1, u16>), gG, blkG, 0, stream, xbf, wyb, b_y, ybf, M_, L_, D_);
    // 2. xb = x@w_x + b_x -> xbbf
    hipLaunchKernelGGL((mgemm_kernel<0, u16>), gG, blkG, 0, stream, xbf, wxb, b_x, xbbf, M_, L_, D_);
    // casts for stage 2 (xbf region now dead)
    hipLaunchKernelGGL(transcast_kernel, gT, blk, 0, stream, w_ig, wigb, L_, L_);
    hipLaunchKernelGGL(transcast_kernel, gT, blk, 0, stream, w_ag, wagb, L_, L_);
    // 3. conv(xbbf) -> convb (wyb/wxb region dead)
    hipLaunchKernelGGL(conv_kernel, dim3(gE8), blk, 0, stream, xbbf, cw, cb, convb);
    hipLaunchKernelGGL(transcast_kernel, gT, blk, 0, stream, w_out, woutb, L_, D_);  // xbbf dead
    // 4-5. gates
    hipLaunchKernelGGL((mgemm_kernel<2, u16>), gG, blkG, 0, stream, convb, wigb, b_ig, gx, M_, L_, L_);
    hipLaunchKernelGGL((mgemm_kernel<2, u16>), gG, blkG, 0, stream, convb, wagb, b_ag, ga, M_, L_, L_);
    // 6. RG-LRU pointwise: a -> gx buf, nx -> ga buf
    hipLaunchKernelGGL(rglru_kernel, dim3(gE8), blk, 0, stream, convb, gx, ga, ap);
    // 7-9. chunked scan; pass 3 fuses z = h*y -> zb (wig/wag region dead)
    hipLaunchKernelGGL(scan1_kernel, gScan, blk, 0, stream, gx, ga, Pb, Sb);
    hipLaunchKernelGGL(scan2_kernel, dim3(B_*L_/256), blk, 0, stream, Pb, Sb, Hin, hn);
    hipLaunchKernelGGL(scan3_kernel, gScan, blk, 0, stream, gx, ga, Hin, ybf, zb);
    // 10. out = z @ w_out + b_out -> d_out (f32)
    hipLaunchKernelGGL((mgemm_kernel<0, float>), gG, blkG, 0, stream, zb, woutb, b_out, out, M_, D_, L_);
}

// Round 7
// 544.837 us; speedup vs baseline: 1.0596x; 1.0596x over previous
//
#include <hip/hip_runtime.h>
#include <math.h>

// Problem constants (fixed by the reference)
#define B_ 4
#define T_ 2048
#define D_ 2048
#define L_ 2048
#define KW 4
#define M_ (B_*T_)       // 8192 rows for all GEMMs

typedef unsigned short u16;
typedef unsigned short u16x8 __attribute__((ext_vector_type(8)));
typedef __bf16 bf16x8 __attribute__((ext_vector_type(8)));
typedef float f32x4 __attribute__((ext_vector_type(4)));

__device__ __forceinline__ u16 f2bf(float f) {       // RNE f32 -> bf16 bits
    unsigned u = __float_as_uint(f);
    u += 0x7fffu + ((u >> 16) & 1u);
    return (u16)(u >> 16);
}
__device__ __forceinline__ float bf2f(u16 h) {
    return __uint_as_float(((unsigned)h) << 16);
}
__device__ __forceinline__ float gelu_exact(float v) {
    return 0.5f * v * (1.0f + erff(v * 0.70710678118654752440f));
}
__device__ __forceinline__ float sigmoidf_(float v) {
    return 1.0f / (1.0f + __expf(-v));
}
__device__ __forceinline__ void gload16(const void* g, void* l) {
    __builtin_amdgcn_global_load_lds(
        (const __attribute__((address_space(1))) void*)g,
        (__attribute__((address_space(3))) void*)l,
        16, 0, 0);
}
// Phase boundary barrier with full scheduling fence (rule #18 analog):
// keeps every ds_read / gload / MFMA pinned inside its phase.
__device__ __forceinline__ void pbar() {
    __builtin_amdgcn_sched_barrier(0);
    __builtin_amdgcn_s_barrier();
    __builtin_amdgcn_sched_barrier(0);
}

// ---------------- cast x -> bf16 ----------------
__global__ __launch_bounds__(256)
void castx_kernel(const float* __restrict__ in, u16* __restrict__ out)
{
    const int i = blockIdx.x * 256 + threadIdx.x;      // one float4
    float4 v = ((const float4*)in)[i];
    ushort4 o;
    o.x = f2bf(v.x); o.y = f2bf(v.y); o.z = f2bf(v.z); o.w = f2bf(v.w);
    ((ushort4*)out)[i] = o;
}

// ---------------- transpose-cast weight [K,N] f32 -> [N,K] bf16 ----------------
__global__ __launch_bounds__(256)
void transcast_kernel(const float* __restrict__ in, u16* __restrict__ out,
                      int Kd, int Nd)
{
    __shared__ float tile[32][33];
    const int bx = blockIdx.x;          // along N
    const int by = blockIdx.y;          // along K
    const int tx = threadIdx.x & 31;
    const int ty = threadIdx.x >> 5;    // 0..7
    #pragma unroll
    for (int j = 0; j < 4; ++j) {
        const int r = by*32 + ty + j*8;
        tile[ty + j*8][tx] = in[(size_t)r * Nd + bx*32 + tx];
    }
    __syncthreads();
    #pragma unroll
    for (int j = 0; j < 4; ++j) {
        const int n = bx*32 + ty + j*8;
        out[(size_t)n * Kd + by*32 + tx] = f2bf(tile[tx][ty + j*8]);
    }
}

// =====================================================================
// bf16 MFMA GEMM — m201 8-phase template port.
// C[M,N] = epi(A[M,K] @ BT[N,K]^T + bias)
// 256x256 tile, BK=64, 8 waves (2M x 4N), per-wave 128x64, 512 threads.
// LDS 128 KB: A 2x32KB dbuf + B 2x32KB dbuf. 4 phases per K-tile, each:
//   { ds_reads | stage gloads | barrier | lgkmcnt(0)+sched_barrier |
//     setprio(1) 16 MFMA setprio(0) | [vmcnt at ph4] | barrier }
// ds_reads/phase = {12, 4, 8, 0}; read latency hides under the barrier
// (wait is AFTER the barrier, m201 ordering).
//
// Quadrants: ph1=(mh0,nh0) ph2=(mh0,nh1) ph3=(mh1,nh1) ph4=(mh1,nh0).
// Region liveness (stage kt(g+2) into buf[g&1] only after consumption):
//   AH0 (rows 0-63,128-191) read-issued ph1, complete before ph1-end bar
//       -> staged ph2.   BH0 (cols 0-31 mod 64) read ph1 -> staged ph3.
//   BH1 read ph2 -> staged ph4.   AH1 read ph3 -> staged ph4.
// vmcnt ledger (8 loads/thread/K-tile: AH0 2, BH0 2, AH1 2, BH1 2):
//   end of K-tile g: outstanding = kt(g+1)'s 8 (staged in K-tile g-1) +
//   kt(g+2)'s 8 (staged this K-tile) = 16; vmcnt(8) BEFORE the ph4-end
//   barrier retires exactly kt(g+1) (per-wave counter; wait must precede
//   barrier for cross-wave visibility — round-5 lesson). Tail: g=NT-2 ->
//   vmcnt(0); g=NT-1 -> nothing outstanding.
// Prologue: stage kt0+kt1 (16 loads), vmcnt(8) retires kt0, barrier.
// =====================================================================
__device__ __forceinline__ void store_out(float* C, size_t idx, float v) { C[idx] = v; }
__device__ __forceinline__ void store_out(u16*   C, size_t idx, float v) { C[idx] = f2bf(v); }

template<int EPI, typename OutT>   // EPI: 0 = bias, 1 = gelu, 2 = sigmoid
__global__ __launch_bounds__(512)
void mgemm_kernel(const u16* __restrict__ A, const u16* __restrict__ BT,
                  const float* __restrict__ bias, OutT* __restrict__ C,
                  int M, int N, int K)
{
    __shared__ __align__(16) u16 lds[65536];   // A: 2x16384 elems | B: 2x16384 elems
    u16* ldsA = lds;
    u16* ldsB = lds + 32768;

    const int tid  = threadIdx.x;
    const int wave = tid >> 6;          // 0..7
    const int lane = tid & 63;

    // bijective XCD swizzle (nwg = 256, %8 == 0)
    const int nbx = N >> 8;                       // N/256
    const int nwg = nbx * (M >> 8);
    const int bid = blockIdx.x;
    const int li  = (bid & 7) * (nwg >> 3) + (bid >> 3);
    const int bm  = (li / nbx) * 256;
    const int bn  = (li % nbx) * 256;

    const int wm = wave >> 2;           // 0..1 (M half: 128 rows)
    const int wn = wave & 3;            // 0..3 (N quarter: 64 cols)
    const int lr = lane & 15;
    const int q  = lane >> 4;
    const int sw = lane & 7;

    const int grow8 = lane >> 3;              // row within 8-row chunk
    const int gslot = (lane & 7) ^ grow8;     // pre-swizzled global k-slot

    const int NT = K >> 6;              // 32 K-tiles

    // ---- staging: A 32 chunks (8 rows x 128B); wave w owns {w,w+16} (AH0:
    //      rows 0-63,128-191) and {w+8,w+24} (AH1). B 32 chunks; c1 =
    //      (w&3)+(w>>2)*8; BH0 = {c1,c1+16} (cols 0-31 mod 64), BH1 = {+4,+20}.
    const int c1 = (wave & 3) + (wave >> 2) * 8;
    const u16* gA0 = A  + (size_t)(bm + (wave     )*8 + grow8) * K + gslot*8;
    const u16* gA1 = A  + (size_t)(bm + (wave + 16)*8 + grow8) * K + gslot*8;
    const u16* gA2 = A  + (size_t)(bm + (wave +  8)*8 + grow8) * K + gslot*8;
    const u16* gA3 = A  + (size_t)(bm + (wave + 24)*8 + grow8) * K + gslot*8;
    const u16* gB0 = BT + (size_t)(bn + (c1       )*8 + grow8) * K + gslot*8;
    const u16* gB1 = BT + (size_t)(bn + (c1  + 16 )*8 + grow8) * K + gslot*8;
    const u16* gB2 = BT + (size_t)(bn + (c1  +  4 )*8 + grow8) * K + gslot*8;
    const u16* gB3 = BT + (size_t)(bn + (c1  + 20 )*8 + grow8) * K + gslot*8;
    const int dA0 = (wave     )*512 + lane*8, dA1 = (wave + 16)*512 + lane*8;
    const int dA2 = (wave +  8)*512 + lane*8, dA3 = (wave + 24)*512 + lane*8;
    const int dB0 = (c1       )*512 + lane*8, dB1 = (c1  + 16 )*512 + lane*8;
    const int dB2 = (c1  +  4 )*512 + lane*8, dB3 = (c1  + 20 )*512 + lane*8;

    auto ST_AH0 = [&](int g){ u16* b = ldsA + (g&1)*16384; const size_t kg = (size_t)g<<6;
        gload16(gA0+kg, &b[dA0]); gload16(gA1+kg, &b[dA1]); };
    auto ST_AH1 = [&](int g){ u16* b = ldsA + (g&1)*16384; const size_t kg = (size_t)g<<6;
        gload16(gA2+kg, &b[dA2]); gload16(gA3+kg, &b[dA3]); };
    auto ST_BH0 = [&](int g){ u16* b = ldsB + (g&1)*16384; const size_t kg = (size_t)g<<6;
        gload16(gB0+kg, &b[dB0]); gload16(gB1+kg, &b[dB1]); };
    auto ST_BH1 = [&](int g){ u16* b = ldsB + (g&1)*16384; const size_t kg = (size_t)g<<6;
        gload16(gB2+kg, &b[dB2]); gload16(gB3+kg, &b[dB3]); };

    // swizzled read slots: global slot s of row r lives at LDS slot s^(r&7); r&7==sw
    const int ks0 = ((    q) ^ sw) * 8;
    const int ks1 = ((4 + q) ^ sw) * 8;

    auto LDA4 = [&](const u16* Ab, int half, bf16x8 (&dst)[4][2]) {
        #pragma unroll
        for (int i = 0; i < 4; ++i) {
            const int ro = (wm*128 + half*64 + i*16 + lr) * 64;
            dst[i][0] = *(const bf16x8*)&Ab[ro + ks0];
            dst[i][1] = *(const bf16x8*)&Ab[ro + ks1];
        }
    };
    auto LDB2 = [&](const u16* Bb, int half, bf16x8 (&dst)[2][2]) {
        #pragma unroll
        for (int j = 0; j < 2; ++j) {
            const int ro = (wn*64 + half*32 + j*16 + lr) * 64;
            dst[j][0] = *(const bf16x8*)&Bb[ro + ks0];
            dst[j][1] = *(const bf16x8*)&Bb[ro + ks1];
        }
    };

    f32x4 acc[8][4] = {};
    bf16x8 a0[4][2], a1[4][2], b0[2][2], b1[2][2];

    auto MM16 = [&](bf16x8 (&a)[4][2], bf16x8 (&b)[2][2], int mo, int no) {
        __builtin_amdgcn_s_setprio(1);
        #pragma unroll
        for (int ks = 0; ks < 2; ++ks)      // ks outer: 8 independent accs between dep pairs
            #pragma unroll
            for (int ii = 0; ii < 4; ++ii)
                #pragma unroll
                for (int jj = 0; jj < 2; ++jj)
                    acc[mo+ii][no+jj] = __builtin_amdgcn_mfma_f32_16x16x32_bf16(
                        a[ii][ks], b[jj][ks], acc[mo+ii][no+jj], 0, 0, 0);
        __builtin_amdgcn_s_setprio(0);
    };

    #define LGKM0() do { asm volatile("s_waitcnt lgkmcnt(0)" ::: "memory"); \
                         __builtin_amdgcn_sched_barrier(0); } while(0)

    // ---- prologue: kt0 + kt1 (16 loads); retire kt0 ----
    ST_AH0(0); ST_BH0(0); ST_AH1(0); ST_BH1(0);
    ST_AH0(1); ST_BH0(1); ST_AH1(1); ST_BH1(1);
    asm volatile("s_waitcnt vmcnt(8)" ::: "memory");
    pbar();

    for (int g = 0; g < NT; ++g) {
        const u16* Ab = ldsA + (g&1)*16384;
        const u16* Bb = ldsB + (g&1)*16384;
        const bool s1 = (g + 1 < NT), s2 = (g + 2 < NT);

        // ph1 (mh0,nh0): 12 ds_reads, no stage
        LDA4(Ab, 0, a0);
        LDB2(Bb, 0, b0);
        pbar();
        LGKM0();
        MM16(a0, b0, 0, 0);
        pbar();

        // ph2 (mh0,nh1): 4 ds_reads | stage AH0(g+2)
        LDB2(Bb, 1, b1);
        if (s2) ST_AH0(g + 2);
        pbar();
        LGKM0();
        MM16(a0, b1, 0, 2);
        pbar();

        // ph3 (mh1,nh1): 8 ds_reads | stage BH0(g+2)
        LDA4(Ab, 1, a1);
        if (s2) ST_BH0(g + 2);
        pbar();
        LGKM0();
        MM16(a1, b1, 4, 2);
        pbar();

        // ph4 (mh1,nh0): 0 ds_reads | stage AH1+BH1(g+2) | K-tile vmcnt
        if (s2) { ST_AH1(g + 2); ST_BH1(g + 2); }
        pbar();
        MM16(a1, b0, 4, 0);
        if (s2)      { asm volatile("s_waitcnt vmcnt(8)" ::: "memory"); }
        else if (s1) { asm volatile("s_waitcnt vmcnt(0)" ::: "memory"); }
        pbar();
    }

    // ---- epilogue; C/D layout: col = lane&15, row = (lane>>4)*4 + reg ----
    // nj innermost: each 16-lane group completes 256 contiguous bytes.
    const int orow = (lane >> 4) * 4;
    float bv[4];
    #pragma unroll
    for (int nj = 0; nj < 4; ++nj) bv[nj] = bias[bn + wn*64 + nj*16 + lr];
    #pragma unroll
    for (int mi = 0; mi < 8; ++mi) {
        #pragma unroll
        for (int r = 0; r < 4; ++r) {
            const int row = bm + wm*128 + mi*16 + orow + r;
            const size_t rb = (size_t)row * N + bn + wn*64 + lr;
            #pragma unroll
            for (int nj = 0; nj < 4; ++nj) {
                float v = acc[mi][nj][r] + bv[nj];
                if (EPI == 1)      v = gelu_exact(v);
                else if (EPI == 2) v = sigmoidf_(v);
                store_out(C, rb + nj*16, v);
            }
        }
    }
    #undef LGKM0
}

// ---------------- causal depthwise conv1d, width 4 (bf16 in/out) ----------------
__global__ __launch_bounds__(256)
void conv_kernel(const u16* __restrict__ xb, const float* __restrict__ cw,
                 const float* __restrict__ cb, u16* __restrict__ out)
{
    const int idx = blockIdx.x * 256 + threadIdx.x;    // one 8-elem chunk
    const int NL8 = L_ / 8;
    const int l = (idx % NL8) * 8;
    const int bt = idx / NL8;
    const int t = bt & (T_ - 1);
    float acc[8];
    #pragma unroll
    for (int j = 0; j < 8; ++j) acc[j] = cb[l + j];
    #pragma unroll
    for (int k = 0; k < KW; ++k) {
        const int ts = t - (KW-1) + k;
        if (ts >= 0) {
            u16x8 xv = *(const u16x8*)(xb + ((size_t)(bt - (KW-1-k))) * L_ + l);
            #pragma unroll
            for (int j = 0; j < 8; ++j)
                acc[j] = fmaf(cw[k*L_ + l + j], bf2f(xv[j]), acc[j]);
        }
    }
    u16x8 o;
    #pragma unroll
    for (int j = 0; j < 8; ++j) o[j] = f2bf(acc[j]);
    *(u16x8*)(out + (size_t)bt * L_ + l) = o;
}

// ---------------- RG-LRU pointwise (in-place: gx->a, ga->nx), bf16 ----------------
__global__ __launch_bounds__(256)
void rglru_kernel(const u16* __restrict__ conv, u16* __restrict__ gxa,
                  u16* __restrict__ ganx, const float* __restrict__ ap)
{
    const int idx = blockIdx.x * 256 + threadIdx.x;
    const int NL8 = L_ / 8;
    const int l = (idx % NL8) * 8;
    const int bt = idx / NL8;
    const int t = bt & (T_ - 1);
    const size_t off = (size_t)bt * L_ + l;
    u16x8 gx = *(u16x8*)(gxa + off);
    u16x8 ga = *(u16x8*)(ganx + off);
    u16x8 cv = *(const u16x8*)(conv + off);
    u16x8 av, nxv;
    #pragma unroll
    for (int j = 0; j < 8; ++j) {
        float p  = ap[l + j];
        float sp = log1pf(expf(p));             // softplus(a_param)
        float la = -8.0f * bf2f(ga[j]) * sp;    // log_a
        float a  = expf(la);
        float mult = sqrtf(fmaxf(0.f, 1.0f - a*a));
        if (t == 0) { a = 0.f; mult = 1.f; }
        av[j]  = f2bf(a);
        nxv[j] = f2bf(bf2f(gx[j]) * bf2f(cv[j]) * mult);
    }
    *(u16x8*)(gxa + off)  = av;
    *(u16x8*)(ganx + off) = nxv;
}

// ---------------- chunked linear scan: h_t = a_t*h_{t-1} + x_t ----------------
#define CHUNKS 32
#define CLEN (T_ / CHUNKS)   // 64

__global__ __launch_bounds__(256)
void scan1_kernel(const u16* __restrict__ Ab, const u16* __restrict__ Xb,
                  float* __restrict__ Pb, float* __restrict__ Sb)
{
    const int l = blockIdx.x * 256 + threadIdx.x;
    const int c = blockIdx.y;
    const int b = blockIdx.z;
    size_t base = ((size_t)b * T_ + (size_t)c * CLEN) * L_ + l;
    float h = 0.f, P = 1.f;
    #pragma unroll 4
    for (int t = 0; t < CLEN; ++t) {
        float a = bf2f(Ab[base + (size_t)t * L_]);
        float x = bf2f(Xb[base + (size_t)t * L_]);
        h = fmaf(a, h, x);
        P *= a;
    }
    const size_t o = ((size_t)b * CHUNKS + c) * L_ + l;
    Pb[o] = P;
    Sb[o] = h;
}

__global__ __launch_bounds__(256)
void scan2_kernel(const float* __restrict__ Pb, const float* __restrict__ Sb,
                  float* __restrict__ Hin, float* __restrict__ hn)
{
    const int idx = blockIdx.x * 256 + threadIdx.x;  // B*L threads
    const int l = idx & (L_ - 1);
    const int b = idx >> 11;
    float h = 0.f;
    for (int c = 0; c < CHUNKS; ++c) {
        const size_t o = ((size_t)b * CHUNKS + c) * L_ + l;
        Hin[o] = h;
        h = fmaf(Pb[o], h, Sb[o]);
    }
    hn[(size_t)b * L_ + l] = h;
}

__global__ __launch_bounds__(256)
void scan3_kernel(const u16* __restrict__ Ab, const u16* __restrict__ Xb,
                  const float* __restrict__ Hin, const u16* __restrict__ Yb,
                  u16* __restrict__ Zb)
{
    const int l = blockIdx.x * 256 + threadIdx.x;
    const int c = blockIdx.y;
    const int b = blockIdx.z;
    float h = Hin[((size_t)b * CHUNKS + c) * L_ + l];
    size_t base = ((size_t)b * T_ + (size_t)c * CLEN) * L_ + l;
    #pragma unroll 4
    for (int t = 0; t < CLEN; ++t) {
        const size_t o = base + (size_t)t * L_;
        h = fmaf(bf2f(Ab[o]), h, bf2f(Xb[o]));
        Zb[o] = f2bf(h * bf2f(Yb[o]));
    }
}

// ---------------- launch ----------------
extern "C" void kernel_launch(void* const* d_in, const int* in_sizes, int n_in,
                              void* d_out, int out_size, void* d_ws, size_t ws_size,
                              hipStream_t stream)
{
    const float* x     = (const float*)d_in[0];
    const float* w_y   = (const float*)d_in[1];
    const float* b_y   = (const float*)d_in[2];
    const float* w_x   = (const float*)d_in[3];
    const float* b_x   = (const float*)d_in[4];
    const float* cw    = (const float*)d_in[5];
    const float* cb    = (const float*)d_in[6];
    const float* ap    = (const float*)d_in[7];
    const float* w_ig  = (const float*)d_in[8];
    const float* b_ig  = (const float*)d_in[9];
    const float* w_ag  = (const float*)d_in[10];
    const float* b_ag  = (const float*)d_in[11];
    const float* w_out = (const float*)d_in[12];
    const float* b_out = (const float*)d_in[13];

    float* out = (float*)d_out;               // [B,T,D] flat
    float* hn  = out + (size_t)M_ * D_;       // [B,L] appended

    // workspace layout (liveness-aliased, peak 192 MB)
    const size_t MB = 1u << 20;
    char* w = (char*)d_ws;
    u16*  xbf   = (u16*)(w + 0);        // [M,D] bf16 — dead after GEMM2
    u16*  wigb  = (u16*)(w + 0);        // [L,L]T bf16 — after xbf dead
    u16*  wagb  = (u16*)(w + 8*MB);
    u16*  zb    = (u16*)(w + 0);        // [M,L] bf16 — after GEMM4
    u16*  ybf   = (u16*)(w + 32*MB);    // [M,L] bf16
    u16*  xbbf  = (u16*)(w + 64*MB);    // [M,L] bf16 — dead after conv
    u16*  woutb = (u16*)(w + 64*MB);    // after xbbf dead
    float* Pb   = (float*)(w + 72*MB);
    float* Sb   = (float*)(w + 73*MB);
    float* Hin  = (float*)(w + 74*MB);
    u16*  wyb   = (u16*)(w + 96*MB);    // weights dead after GEMM2
    u16*  wxb   = (u16*)(w + 104*MB);
    u16*  convb = (u16*)(w + 96*MB);    // [M,L] bf16 — after wyb/wxb dead
    u16*  gx    = (u16*)(w + 128*MB);   // -> a  (in-place)
    u16*  ga    = (u16*)(w + 160*MB);   // -> nx (in-place)

    const dim3 blk(256);
    const dim3 blkG(512);
    const dim3 gG((L_/256) * (M_/256));             // 256 blocks = 1/CU
    const dim3 gT(2048/32, 2048/32);                // transpose grids
    const int  gE8 = (M_ * L_ / 8) / 256;           // 8-wide elementwise
    const dim3 gScan(L_/256, CHUNKS, B_);

    // casts for stage 1
    hipLaunchKernelGGL(castx_kernel, dim3((M_*D_/4)/256), blk, 0, stream, x, xbf);
    hipLaunchKernelGGL(transcast_kernel, gT, blk, 0, stream, w_y, wyb, D_, L_);
    hipLaunchKernelGGL(transcast_kernel, gT, blk, 0, stream, w_x, wxb, D_, L_);
    // 1. y = GELU(x@w_y + b_y) -> ybf
    hipLaunchKernelGGL((mgemm_kernel<1, u16>), gG, blkG, 0, stream, xbf, wyb, b_y, ybf, M_, L_, D_);
    // 2. xb = x@w_x + b_x -> xbbf
    hipLaunchKernelGGL((mgemm_kernel<0, u16>), gG, blkG, 0, stream, xbf, wxb, b_x, xbbf, M_, L_, D_);
    // casts for stage 2 (xbf region now dead)
    hipLaunchKernelGGL(transcast_kernel, gT, blk, 0, stream, w_ig, wigb, L_, L_);
    hipLaunchKernelGGL(transcast_kernel, gT, blk, 0, stream, w_ag, wagb, L_, L_);
    // 3. conv(xbbf) -> convb (wyb/wxb region dead)
    hipLaunchKernelGGL(conv_kernel, dim3(gE8), blk, 0, stream, xbbf, cw, cb, convb);
    hipLaunchKernelGGL(transcast_kernel, gT, blk, 0, stream, w_out, woutb, L_, D_);  // xbbf dead
    // 4-5. gates
    hipLaunchKernelGGL((mgemm_kernel<2, u16>), gG, blkG, 0, stream, convb, wigb, b_ig, gx, M_, L_, L_);
    hipLaunchKernelGGL((mgemm_kernel<2, u16>), gG, blkG, 0, stream, convb, wagb, b_ag, ga, M_, L_, L_);
    // 6. RG-LRU pointwise: a -> gx buf, nx -> ga buf
    hipLaunchKernelGGL(rglru_kernel, dim3(gE8), blk, 0, stream, convb, gx, ga, ap);
    // 7-9. chunked scan; pass 3 fuses z = h*y -> zb (wig/wag region dead)
    hipLaunchKernelGGL(scan1_kernel, gScan, blk, 0, stream, gx, ga, Pb, Sb);
    hipLaunchKernelGGL(scan2_kernel, dim3(B_*L_/256), blk, 0, stream, Pb, Sb, Hin, hn);
    hipLaunchKernelGGL(scan3_kernel, gScan, blk, 0, stream, gx, ga, Hin, ybf, zb);
    // 10. out = z @ w_out + b_out -> d_out (f32)
    hipLaunchKernelGGL((mgemm_kernel<0, float>), gG, blkG, 0, stream, zb, woutb, b_out, out, M_, D_, L_);
}

// Round 8
// 544.574 us; speedup vs baseline: 1.0602x; 1.0005x over previous
//
#include <hip/hip_runtime.h>
#include <math.h>

// Problem constants (fixed by the reference)
#define B_ 4
#define T_ 2048
#define D_ 2048
#define L_ 2048
#define KW 4
#define M_ (B_*T_)       // 8192 rows for all GEMMs

typedef unsigned short u16;
typedef unsigned short u16x8 __attribute__((ext_vector_type(8)));
typedef __bf16 bf16x8 __attribute__((ext_vector_type(8)));
typedef float f32x4 __attribute__((ext_vector_type(4)));

__device__ __forceinline__ u16 f2bf(float f) {       // RNE f32 -> bf16 bits
    unsigned u = __float_as_uint(f);
    u += 0x7fffu + ((u >> 16) & 1u);
    return (u16)(u >> 16);
}
__device__ __forceinline__ float bf2f(u16 h) {
    return __uint_as_float(((unsigned)h) << 16);
}
__device__ __forceinline__ float gelu_exact(float v) {
    return 0.5f * v * (1.0f + erff(v * 0.70710678118654752440f));
}
__device__ __forceinline__ float sigmoidf_(float v) {
    return 1.0f / (1.0f + __expf(-v));
}
__device__ __forceinline__ void gload16(const void* g, void* l) {
    __builtin_amdgcn_global_load_lds(
        (const __attribute__((address_space(1))) void*)g,
        (__attribute__((address_space(3))) void*)l,
        16, 0, 0);
}
// Phase boundary: RAW s_barrier, no sched_barrier fences (m141: fences on
// every boundary cost 1.7x by defeating compiler scheduling). s_barrier is
// itself a scheduling-region boundary at MIR level; cross-wave staging
// visibility is carried by the asm "memory"-clobbered waitcnts placed
// BEFORE the barrier (round-5/6 verified pattern).
__device__ __forceinline__ void bar() {
    __builtin_amdgcn_s_barrier();
}

// ---------------- cast x -> bf16 ----------------
__global__ __launch_bounds__(256)
void castx_kernel(const float* __restrict__ in, u16* __restrict__ out)
{
    const int i = blockIdx.x * 256 + threadIdx.x;      // one float4
    float4 v = ((const float4*)in)[i];
    ushort4 o;
    o.x = f2bf(v.x); o.y = f2bf(v.y); o.z = f2bf(v.z); o.w = f2bf(v.w);
    ((ushort4*)out)[i] = o;
}

// ---------------- transpose-cast weight [K,N] f32 -> [N,K] bf16 ----------------
__global__ __launch_bounds__(256)
void transcast_kernel(const float* __restrict__ in, u16* __restrict__ out,
                      int Kd, int Nd)
{
    __shared__ float tile[32][33];
    const int bx = blockIdx.x;          // along N
    const int by = blockIdx.y;          // along K
    const int tx = threadIdx.x & 31;
    const int ty = threadIdx.x >> 5;    // 0..7
    #pragma unroll
    for (int j = 0; j < 4; ++j) {
        const int r = by*32 + ty + j*8;
        tile[ty + j*8][tx] = in[(size_t)r * Nd + bx*32 + tx];
    }
    __syncthreads();
    #pragma unroll
    for (int j = 0; j < 4; ++j) {
        const int n = bx*32 + ty + j*8;
        out[(size_t)n * Kd + by*32 + tx] = f2bf(tile[tx][ty + j*8]);
    }
}

// =====================================================================
// bf16 MFMA GEMM — m201 8-phase template port, round 8: identical to
// round 7 EXCEPT all sched_barrier(0) fences removed (single-variable
// A/B vs r7; m141 evidence says the fences cost ~1.7x).
// C[M,N] = epi(A[M,K] @ BT[N,K]^T + bias)
// 256x256 tile, BK=64, 8 waves (2M x 4N), per-wave 128x64, 512 threads.
// LDS 128 KB: A 2x32KB dbuf + B 2x32KB dbuf. 4 phases per K-tile:
//   { ds_reads | stage gloads | barrier | lgkmcnt(0) |
//     setprio(1) 16 MFMA setprio(0) | [vmcnt at ph4] | barrier }
// Quadrants: ph1=(mh0,nh0) ph2=(mh0,nh1) ph3=(mh1,nh1) ph4=(mh1,nh0);
// ds_reads/phase = {12, 4, 8, 0}.
// Region liveness (stage kt(g+2) into buf[g&1] only after consumption):
//   AH0 read ph1 -> staged ph2; BH0 read ph1 -> staged ph3;
//   BH1 read ph2 -> staged ph4; AH1 read ph3 -> staged ph4.
// vmcnt ledger (8 loads/thread/K-tile): end of K-tile g, outstanding =
//   kt(g+1)'s 8 + kt(g+2)'s 8 = 16; vmcnt(8) BEFORE the ph4-end barrier
//   retires exactly kt(g+1) (per-wave counter; wait precedes barrier for
//   cross-wave visibility — round-5 lesson). Tail: g=NT-2 -> vmcnt(0).
// Prologue: stage kt0+kt1 (16 loads), vmcnt(8) retires kt0, barrier.
// =====================================================================
__device__ __forceinline__ void store_out(float* C, size_t idx, float v) { C[idx] = v; }
__device__ __forceinline__ void store_out(u16*   C, size_t idx, float v) { C[idx] = f2bf(v); }

template<int EPI, typename OutT>   // EPI: 0 = bias, 1 = gelu, 2 = sigmoid
__global__ __launch_bounds__(512)
void mgemm_kernel(const u16* __restrict__ A, const u16* __restrict__ BT,
                  const float* __restrict__ bias, OutT* __restrict__ C,
                  int M, int N, int K)
{
    __shared__ __align__(16) u16 lds[65536];   // A: 2x16384 elems | B: 2x16384 elems
    u16* ldsA = lds;
    u16* ldsB = lds + 32768;

    const int tid  = threadIdx.x;
    const int wave = tid >> 6;          // 0..7
    const int lane = tid & 63;

    // bijective XCD swizzle (nwg = 256, %8 == 0)
    const int nbx = N >> 8;                       // N/256
    const int nwg = nbx * (M >> 8);
    const int bid = blockIdx.x;
    const int li  = (bid & 7) * (nwg >> 3) + (bid >> 3);
    const int bm  = (li / nbx) * 256;
    const int bn  = (li % nbx) * 256;

    const int wm = wave >> 2;           // 0..1 (M half: 128 rows)
    const int wn = wave & 3;            // 0..3 (N quarter: 64 cols)
    const int lr = lane & 15;
    const int q  = lane >> 4;
    const int sw = lane & 7;

    const int grow8 = lane >> 3;              // row within 8-row chunk
    const int gslot = (lane & 7) ^ grow8;     // pre-swizzled global k-slot

    const int NT = K >> 6;              // 32 K-tiles

    // ---- staging: A 32 chunks (8 rows x 128B); wave w owns {w,w+16} (AH0:
    //      rows 0-63,128-191) and {w+8,w+24} (AH1). B 32 chunks; c1 =
    //      (w&3)+(w>>2)*8; BH0 = {c1,c1+16} (cols 0-31 mod 64), BH1 = {+4,+20}.
    const int c1 = (wave & 3) + (wave >> 2) * 8;
    const u16* gA0 = A  + (size_t)(bm + (wave     )*8 + grow8) * K + gslot*8;
    const u16* gA1 = A  + (size_t)(bm + (wave + 16)*8 + grow8) * K + gslot*8;
    const u16* gA2 = A  + (size_t)(bm + (wave +  8)*8 + grow8) * K + gslot*8;
    const u16* gA3 = A  + (size_t)(bm + (wave + 24)*8 + grow8) * K + gslot*8;
    const u16* gB0 = BT + (size_t)(bn + (c1       )*8 + grow8) * K + gslot*8;
    const u16* gB1 = BT + (size_t)(bn + (c1  + 16 )*8 + grow8) * K + gslot*8;
    const u16* gB2 = BT + (size_t)(bn + (c1  +  4 )*8 + grow8) * K + gslot*8;
    const u16* gB3 = BT + (size_t)(bn + (c1  + 20 )*8 + grow8) * K + gslot*8;
    const int dA0 = (wave     )*512 + lane*8, dA1 = (wave + 16)*512 + lane*8;
    const int dA2 = (wave +  8)*512 + lane*8, dA3 = (wave + 24)*512 + lane*8;
    const int dB0 = (c1       )*512 + lane*8, dB1 = (c1  + 16 )*512 + lane*8;
    const int dB2 = (c1  +  4 )*512 + lane*8, dB3 = (c1  + 20 )*512 + lane*8;

    auto ST_AH0 = [&](int g){ u16* b = ldsA + (g&1)*16384; const size_t kg = (size_t)g<<6;
        gload16(gA0+kg, &b[dA0]); gload16(gA1+kg, &b[dA1]); };
    auto ST_AH1 = [&](int g){ u16* b = ldsA + (g&1)*16384; const size_t kg = (size_t)g<<6;
        gload16(gA2+kg, &b[dA2]); gload16(gA3+kg, &b[dA3]); };
    auto ST_BH0 = [&](int g){ u16* b = ldsB + (g&1)*16384; const size_t kg = (size_t)g<<6;
        gload16(gB0+kg, &b[dB0]); gload16(gB1+kg, &b[dB1]); };
    auto ST_BH1 = [&](int g){ u16* b = ldsB + (g&1)*16384; const size_t kg = (size_t)g<<6;
        gload16(gB2+kg, &b[dB2]); gload16(gB3+kg, &b[dB3]); };

    // swizzled read slots: global slot s of row r lives at LDS slot s^(r&7); r&7==sw
    const int ks0 = ((    q) ^ sw) * 8;
    const int ks1 = ((4 + q) ^ sw) * 8;

    auto LDA4 = [&](const u16* Ab, int half, bf16x8 (&dst)[4][2]) {
        #pragma unroll
        for (int i = 0; i < 4; ++i) {
            const int ro = (wm*128 + half*64 + i*16 + lr) * 64;
            dst[i][0] = *(const bf16x8*)&Ab[ro + ks0];
            dst[i][1] = *(const bf16x8*)&Ab[ro + ks1];
        }
    };
    auto LDB2 = [&](const u16* Bb, int half, bf16x8 (&dst)[2][2]) {
        #pragma unroll
        for (int j = 0; j < 2; ++j) {
            const int ro = (wn*64 + half*32 + j*16 + lr) * 64;
            dst[j][0] = *(const bf16x8*)&Bb[ro + ks0];
            dst[j][1] = *(const bf16x8*)&Bb[ro + ks1];
        }
    };

    f32x4 acc[8][4] = {};
    bf16x8 a0[4][2], a1[4][2], b0[2][2], b1[2][2];

    auto MM16 = [&](bf16x8 (&a)[4][2], bf16x8 (&b)[2][2], int mo, int no) {
        __builtin_amdgcn_s_setprio(1);
        #pragma unroll
        for (int ks = 0; ks < 2; ++ks)      // ks outer: 8 independent accs between dep pairs
            #pragma unroll
            for (int ii = 0; ii < 4; ++ii)
                #pragma unroll
                for (int jj = 0; jj < 2; ++jj)
                    acc[mo+ii][no+jj] = __builtin_amdgcn_mfma_f32_16x16x32_bf16(
                        a[ii][ks], b[jj][ks], acc[mo+ii][no+jj], 0, 0, 0);
        __builtin_amdgcn_s_setprio(0);
    };

    #define LGKM0() asm volatile("s_waitcnt lgkmcnt(0)" ::: "memory")

    // ---- prologue: kt0 + kt1 (16 loads); retire kt0 ----
    ST_AH0(0); ST_BH0(0); ST_AH1(0); ST_BH1(0);
    ST_AH0(1); ST_BH0(1); ST_AH1(1); ST_BH1(1);
    asm volatile("s_waitcnt vmcnt(8)" ::: "memory");
    bar();

    for (int g = 0; g < NT; ++g) {
        const u16* Ab = ldsA + (g&1)*16384;
        const u16* Bb = ldsB + (g&1)*16384;
        const bool s1 = (g + 1 < NT), s2 = (g + 2 < NT);

        // ph1 (mh0,nh0): 12 ds_reads, no stage
        LDA4(Ab, 0, a0);
        LDB2(Bb, 0, b0);
        bar();
        LGKM0();
        MM16(a0, b0, 0, 0);
        bar();

        // ph2 (mh0,nh1): 4 ds_reads | stage AH0(g+2)
        LDB2(Bb, 1, b1);
        if (s2) ST_AH0(g + 2);
        bar();
        LGKM0();
        MM16(a0, b1, 0, 2);
        bar();

        // ph3 (mh1,nh1): 8 ds_reads | stage BH0(g+2)
        LDA4(Ab, 1, a1);
        if (s2) ST_BH0(g + 2);
        bar();
        LGKM0();
        MM16(a1, b1, 4, 2);
        bar();

        // ph4 (mh1,nh0): 0 ds_reads | stage AH1+BH1(g+2) | K-tile vmcnt
        if (s2) { ST_AH1(g + 2); ST_BH1(g + 2); }
        bar();
        MM16(a1, b0, 4, 0);
        if (s2)      { asm volatile("s_waitcnt vmcnt(8)" ::: "memory"); }
        else if (s1) { asm volatile("s_waitcnt vmcnt(0)" ::: "memory"); }
        bar();
    }

    // ---- epilogue; C/D layout: col = lane&15, row = (lane>>4)*4 + reg ----
    // nj innermost: each 16-lane group completes 256 contiguous bytes.
    const int orow = (lane >> 4) * 4;
    float bv[4];
    #pragma unroll
    for (int nj = 0; nj < 4; ++nj) bv[nj] = bias[bn + wn*64 + nj*16 + lr];
    #pragma unroll
    for (int mi = 0; mi < 8; ++mi) {
        #pragma unroll
        for (int r = 0; r < 4; ++r) {
            const int row = bm + wm*128 + mi*16 + orow + r;
            const size_t rb = (size_t)row * N + bn + wn*64 + lr;
            #pragma unroll
            for (int nj = 0; nj < 4; ++nj) {
                float v = acc[mi][nj][r] + bv[nj];
                if (EPI == 1)      v = gelu_exact(v);
                else if (EPI == 2) v = sigmoidf_(v);
                store_out(C, rb + nj*16, v);
            }
        }
    }
    #undef LGKM0
}

// ---------------- causal depthwise conv1d, width 4 (bf16 in/out) ----------------
__global__ __launch_bounds__(256)
void conv_kernel(const u16* __restrict__ xb, const float* __restrict__ cw,
                 const float* __restrict__ cb, u16* __restrict__ out)
{
    const int idx = blockIdx.x * 256 + threadIdx.x;    // one 8-elem chunk
    const int NL8 = L_ / 8;
    const int l = (idx % NL8) * 8;
    const int bt = idx / NL8;
    const int t = bt & (T_ - 1);
    float acc[8];
    #pragma unroll
    for (int j = 0; j < 8; ++j) acc[j] = cb[l + j];
    #pragma unroll
    for (int k = 0; k < KW; ++k) {
        const int ts = t - (KW-1) + k;
        if (ts >= 0) {
            u16x8 xv = *(const u16x8*)(xb + ((size_t)(bt - (KW-1-k))) * L_ + l);
            #pragma unroll
            for (int j = 0; j < 8; ++j)
                acc[j] = fmaf(cw[k*L_ + l + j], bf2f(xv[j]), acc[j]);
        }
    }
    u16x8 o;
    #pragma unroll
    for (int j = 0; j < 8; ++j) o[j] = f2bf(acc[j]);
    *(u16x8*)(out + (size_t)bt * L_ + l) = o;
}

// ---------------- RG-LRU pointwise (in-place: gx->a, ga->nx), bf16 ----------------
__global__ __launch_bounds__(256)
void rglru_kernel(const u16* __restrict__ conv, u16* __restrict__ gxa,
                  u16* __restrict__ ganx, const float* __restrict__ ap)
{
    const int idx = blockIdx.x * 256 + threadIdx.x;
    const int NL8 = L_ / 8;
    const int l = (idx % NL8) * 8;
    const int bt = idx / NL8;
    const int t = bt & (T_ - 1);
    const size_t off = (size_t)bt * L_ + l;
    u16x8 gx = *(u16x8*)(gxa + off);
    u16x8 ga = *(u16x8*)(ganx + off);
    u16x8 cv = *(const u16x8*)(conv + off);
    u16x8 av, nxv;
    #pragma unroll
    for (int j = 0; j < 8; ++j) {
        float p  = ap[l + j];
        float sp = log1pf(expf(p));             // softplus(a_param)
        float la = -8.0f * bf2f(ga[j]) * sp;    // log_a
        float a  = expf(la);
        float mult = sqrtf(fmaxf(0.f, 1.0f - a*a));
        if (t == 0) { a = 0.f; mult = 1.f; }
        av[j]  = f2bf(a);
        nxv[j] = f2bf(bf2f(gx[j]) * bf2f(cv[j]) * mult);
    }
    *(u16x8*)(gxa + off)  = av;
    *(u16x8*)(ganx + off) = nxv;
}

// ---------------- chunked linear scan: h_t = a_t*h_{t-1} + x_t ----------------
#define CHUNKS 32
#define CLEN (T_ / CHUNKS)   // 64

__global__ __launch_bounds__(256)
void scan1_kernel(const u16* __restrict__ Ab, const u16* __restrict__ Xb,
                  float* __restrict__ Pb, float* __restrict__ Sb)
{
    const int l = blockIdx.x * 256 + threadIdx.x;
    const int c = blockIdx.y;
    const int b = blockIdx.z;
    size_t base = ((size_t)b * T_ + (size_t)c * CLEN) * L_ + l;
    float h = 0.f, P = 1.f;
    #pragma unroll 4
    for (int t = 0; t < CLEN; ++t) {
        float a = bf2f(Ab[base + (size_t)t * L_]);
        float x = bf2f(Xb[base + (size_t)t * L_]);
        h = fmaf(a, h, x);
        P *= a;
    }
    const size_t o = ((size_t)b * CHUNKS + c) * L_ + l;
    Pb[o] = P;
    Sb[o] = h;
}

__global__ __launch_bounds__(256)
void scan2_kernel(const float* __restrict__ Pb, const float* __restrict__ Sb,
                  float* __restrict__ Hin, float* __restrict__ hn)
{
    const int idx = blockIdx.x * 256 + threadIdx.x;  // B*L threads
    const int l = idx & (L_ - 1);
    const int b = idx >> 11;
    float h = 0.f;
    for (int c = 0; c < CHUNKS; ++c) {
        const size_t o = ((size_t)b * CHUNKS + c) * L_ + l;
        Hin[o] = h;
        h = fmaf(Pb[o], h, Sb[o]);
    }
    hn[(size_t)b * L_ + l] = h;
}

__global__ __launch_bounds__(256)
void scan3_kernel(const u16* __restrict__ Ab, const u16* __restrict__ Xb,
                  const float* __restrict__ Hin, const u16* __restrict__ Yb,
                  u16* __restrict__ Zb)
{
    const int l = blockIdx.x * 256 + threadIdx.x;
    const int c = blockIdx.y;
    const int b = blockIdx.z;
    float h = Hin[((size_t)b * CHUNKS + c) * L_ + l];
    size_t base = ((size_t)b * T_ + (size_t)c * CLEN) * L_ + l;
    #pragma unroll 4
    for (int t = 0; t < CLEN; ++t) {
        const size_t o = base + (size_t)t * L_;
        h = fmaf(bf2f(Ab[o]), h, bf2f(Xb[o]));
        Zb[o] = f2bf(h * bf2f(Yb[o]));
    }
}

// ---------------- launch ----------------
extern "C" void kernel_launch(void* const* d_in, const int* in_sizes, int n_in,
                              void* d_out, int out_size, void* d_ws, size_t ws_size,
                              hipStream_t stream)
{
    const float* x     = (const float*)d_in[0];
    const float* w_y   = (const float*)d_in[1];
    const float* b_y   = (const float*)d_in[2];
    const float* w_x   = (const float*)d_in[3];
    const float* b_x   = (const float*)d_in[4];
    const float* cw    = (const float*)d_in[5];
    const float* cb    = (const float*)d_in[6];
    const float* ap    = (const float*)d_in[7];
    const float* w_ig  = (const float*)d_in[8];
    const float* b_ig  = (const float*)d_in[9];
    const float* w_ag  = (const float*)d_in[10];
    const float* b_ag  = (const float*)d_in[11];
    const float* w_out = (const float*)d_in[12];
    const float* b_out = (const float*)d_in[13];

    float* out = (float*)d_out;               // [B,T,D] flat
    float* hn  = out + (size_t)M_ * D_;       // [B,L] appended

    // workspace layout (liveness-aliased, peak 192 MB)
    const size_t MB = 1u << 20;
    char* w = (char*)d_ws;
    u16*  xbf   = (u16*)(w + 0);        // [M,D] bf16 — dead after GEMM2
    u16*  wigb  = (u16*)(w + 0);        // [L,L]T bf16 — after xbf dead
    u16*  wagb  = (u16*)(w + 8*MB);
    u16*  zb    = (u16*)(w + 0);        // [M,L] bf16 — after GEMM4
    u16*  ybf   = (u16*)(w + 32*MB);    // [M,L] bf16
    u16*  xbbf  = (u16*)(w + 64*MB);    // [M,L] bf16 — dead after conv
    u16*  woutb = (u16*)(w + 64*MB);    // after xbbf dead
    float* Pb   = (float*)(w + 72*MB);
    float* Sb   = (float*)(w + 73*MB);
    float* Hin  = (float*)(w + 74*MB);
    u16*  wyb   = (u16*)(w + 96*MB);    // weights dead after GEMM2
    u16*  wxb   = (u16*)(w + 104*MB);
    u16*  convb = (u16*)(w + 96*MB);    // [M,L] bf16 — after wyb/wxb dead
    u16*  gx    = (u16*)(w + 128*MB);   // -> a  (in-place)
    u16*  ga    = (u16*)(w + 160*MB);   // -> nx (in-place)

    const dim3 blk(256);
    const dim3 blkG(512);
    const dim3 gG((L_/256) * (M_/256));             // 256 blocks = 1/CU
    const dim3 gT(2048/32, 2048/32);                // transpose grids
    const int  gE8 = (M_ * L_ / 8) / 256;           // 8-wide elementwise
    const dim3 gScan(L_/256, CHUNKS, B_);

    // casts for stage 1
    hipLaunchKernelGGL(castx_kernel, dim3((M_*D_/4)/256), blk, 0, stream, x, xbf);
    hipLaunchKernelGGL(transcast_kernel, gT, blk, 0, stream, w_y, wyb, D_, L_);
    hipLaunchKernelGGL(transcast_kernel, gT, blk, 0, stream, w_x, wxb, D_, L_);
    // 1. y = GELU(x@w_y + b_y) -> ybf
    hipLaunchKernelGGL((mgemm_kernel<1, u16>), gG, blkG, 0, stream, xbf, wyb, b_y, ybf, M_, L_, D_);
    // 2. xb = x@w_x + b_x -> xbbf
    hipLaunchKernelGGL((mgemm_kernel<0, u16>), gG, blkG, 0, stream, xbf, wxb, b_x, xbbf, M_, L_, D_);
    // casts for stage 2 (xbf region now dead)
    hipLaunchKernelGGL(transcast_kernel, gT, blk, 0, stream, w_ig, wigb, L_, L_);
    hipLaunchKernelGGL(transcast_kernel, gT, blk, 0, stream, w_ag, wagb, L_, L_);
    // 3. conv(xbbf) -> convb (wyb/wxb region dead)
    hipLaunchKernelGGL(conv_kernel, dim3(gE8), blk, 0, stream, xbbf, cw, cb, convb);
    hipLaunchKernelGGL(transcast_kernel, gT, blk, 0, stream, w_out, woutb, L_, D_);  // xbbf dead
    // 4-5. gates
    hipLaunchKernelGGL((mgemm_kernel<2, u16>), gG, blkG, 0, stream, convb, wigb, b_ig, gx, M_, L_, L_);
    hipLaunchKernelGGL((mgemm_kernel<2, u16>), gG, blkG, 0, stream, convb, wagb, b_ag, ga, M_, L_, L_);
    // 6. RG-LRU pointwise: a -> gx buf, nx -> ga buf
    hipLaunchKernelGGL(rglru_kernel, dim3(gE8), blk, 0, stream, convb, gx, ga, ap);
    // 7-9. chunked scan; pass 3 fuses z = h*y -> zb (wig/wag region dead)
    hipLaunchKernelGGL(scan1_kernel, gScan, blk, 0, stream, gx, ga, Pb, Sb);
    hipLaunchKernelGGL(scan2_kernel, dim3(B_*L_/256), blk, 0, stream, Pb, Sb, Hin, hn);
    hipLaunchKernelGGL(scan3_kernel, gScan, blk, 0, stream, gx, ga, Hin, ybf, zb);
    // 10. out = z @ w_out + b_out -> d_out (f32)
    hipLaunchKernelGGL((mgemm_kernel<0, float>), gG, blkG, 0, stream, zb, woutb, b_out, out, M_, D_, L_);
}